// Round 2
// baseline (98.421 us; speedup 1.0000x reference)
//
#include <hip/hip_runtime.h>
#include <stdint.h>
#include <math.h>

#define T_SEQ 8192

typedef int vint4 __attribute__((ext_vector_type(4)));  // native vector: OK for nontemporal builtins

__device__ __forceinline__ uint32_t rotl32(uint32_t x, int n) {
    return (x << n) | (x >> (32 - n));
}

// JAX threefry2x32 with key = (0, 42) (jax.random.key(42)), counts = iota(12288)
// split in half: pair i -> (x0=i, x1=i+6144); bits[idx] = idx<6144 ? y0 : y1.
__device__ uint32_t jax_threefry_bits_12288(uint32_t idx) {
    const uint32_t k0 = 0u, k1 = 42u, k2 = 0u ^ 42u ^ 0x1BD11BDAu;
    uint32_t i = (idx < 6144u) ? idx : (idx - 6144u);
    uint32_t x0 = i + k0;
    uint32_t x1 = (i + 6144u) + k1;
#define TF_R4(a,b,c,d) \
    x0 += x1; x1 = rotl32(x1, a); x1 ^= x0; \
    x0 += x1; x1 = rotl32(x1, b); x1 ^= x0; \
    x0 += x1; x1 = rotl32(x1, c); x1 ^= x0; \
    x0 += x1; x1 = rotl32(x1, d); x1 ^= x0;
    TF_R4(13, 15, 26, 6);   x0 += k1; x1 += k2 + 1u;
    TF_R4(17, 29, 16, 24);  x0 += k2; x1 += k0 + 2u;
    TF_R4(13, 15, 26, 6);   x0 += k0; x1 += k1 + 3u;
    TF_R4(17, 29, 16, 24);  x0 += k1; x1 += k2 + 4u;
    TF_R4(13, 15, 26, 6);   x0 += k2; x1 += k0 + 5u;
#undef TF_R4
    return (idx < 6144u) ? x0 : x1;
}

// R1: 4 rows per block, 256 blocks x 1024 threads (16 waves/CU, unchanged wave count).
// Rationale: phases 2/3 re-read W1+W2 (281 KB) per block; at 512 blocks that's
// ~144 MB of L2 traffic serialized after the HBM phase (~4 us). With 4 rows/block
// and explicit 4-row register reuse of each weight element, unique weight reads
// drop ~4x and each k-split thread carries 4 independent FMA chains.
// Phase 1 (HBM-bound token stream) is per-thread identical to the verified kernel.
__global__ __launch_bounds__(1024) void fused_kernel(const int* __restrict__ tok,
                                                     const float* __restrict__ W1,
                                                     const float* __restrict__ b1,
                                                     const float* __restrict__ W2,
                                                     const float* __restrict__ b2,
                                                     float* __restrict__ out) {
    const int tid = threadIdx.x;
    const int wave = tid >> 6;   // 0..15
    const int hw = tid >> 5;     // 0..31 (half-wave-private histogram)
    const int r0 = blockIdx.x * 4;

    __shared__ int hist[32][128];       // 16 KB
    __shared__ int wsum[16];
    __shared__ unsigned wsq[16];
    __shared__ float s[4][150];         // stats rows
    __shared__ float h[4][256];         // hidden layer
    __shared__ float part1[4][4][256];  // [kq][row][col] layer-1 k-split partials, 16 KB
    __shared__ float part2[4][4][128];  // [kq][row][col] layer-2 k-split partials, 8 KB

    // zero histograms (4096 ints, 4 per thread)
    for (int i = tid; i < 4096; i += 1024) ((int*)hist)[i] = 0;
    __syncthreads();

    // ---- phase 1: token stream -> hist / sum / sumsq ----
    {
        const int row_local = tid >> 8;   // 0..3
        const int t256 = tid & 255;       // thread id within the row's 256-thread group
        const vint4* tp = (const vint4*)(tok + (size_t)(r0 + row_local) * T_SEQ);

        // batch-load: 8x global_load_dwordx4 issued back-to-back (32 VGPRs),
        // static indices only (full unroll) so the array stays in registers.
        vint4 v[8];
#pragma unroll
        for (int j = 0; j < 8; ++j)
            v[j] = __builtin_nontemporal_load(&tp[j * 256 + t256]); // single-use stream

        int sum = 0;
        unsigned sq = 0;
#pragma unroll
        for (int j = 0; j < 8; ++j) {
            atomicAdd(&hist[hw][v[j].x & 127], 1); sum += v[j].x; sq += (unsigned)__mul24(v[j].x, v[j].x);
            atomicAdd(&hist[hw][v[j].y & 127], 1); sum += v[j].y; sq += (unsigned)__mul24(v[j].y, v[j].y);
            atomicAdd(&hist[hw][v[j].z & 127], 1); sum += v[j].z; sq += (unsigned)__mul24(v[j].z, v[j].z);
            atomicAdd(&hist[hw][v[j].w & 127], 1); sum += v[j].w; sq += (unsigned)__mul24(v[j].w, v[j].w);
        }
        // 64-lane wave reduction; both sums fit in 32 bits (max sumsq ~1.25e9 < 2^31)
#pragma unroll
        for (int off = 32; off > 0; off >>= 1) {
            sum += __shfl_down(sum, off);
            sq  += __shfl_down(sq, off);
        }
        if ((tid & 63) == 0) { wsum[wave] = sum; wsq[wave] = sq; }
    }
    __syncthreads();

    // ---- stats assembly into LDS (600 active threads: 4 rows x 150 dims) ----
    if (tid < 600) {
        const int r = tid / 150;
        const int k = tid - r * 150;
        const int wb = r * 4;      // wave base for wsum/wsq
        const int hb = r * 8;      // half-wave base for hist
        float val;
        if (k < 128) {
            int hh = (hist[hb][k] + hist[hb + 1][k]) + (hist[hb + 2][k] + hist[hb + 3][k])
                   + (hist[hb + 4][k] + hist[hb + 5][k]) + (hist[hb + 6][k] + hist[hb + 7][k]);
            // reference divisor (8192.0f + 1e-8f) == 8192.0f exactly in fp32
            val = (float)hh * (1.0f / 8192.0f);
        } else if (k == 128) {
            int ss = wsum[wb] + wsum[wb + 1] + wsum[wb + 2] + wsum[wb + 3];
            val = (float)ss * (1.0f / 8192.0f);  // exact: ss < 2^24, / 2^13
        } else if (k == 129) {
            double ss = (double)(wsum[wb] + wsum[wb + 1] + wsum[wb + 2] + wsum[wb + 3]);
            double qq = (double)wsq[wb] + (double)wsq[wb + 1] + (double)wsq[wb + 2] + (double)wsq[wb + 3];
            val = (float)sqrt((qq - ss * ss / 8192.0) / 8191.0);  // unbiased (T-1)
        } else if (k < 138) {
            val = 0.0f;  // rhythm dims 2..9
        } else {
            uint32_t bits = jax_threefry_bits_12288((uint32_t)(r0 + r) * 12u + (uint32_t)(k - 138));
            val = __uint_as_float((bits >> 9) | 0x3f800000u) - 1.0f;
        }
        s[r][k] = val;
    }
    __syncthreads();

    // ---- phase 2: layer 1, k-split 4 ways x 256 cols; each W1 element read once,
    //      used for all 4 rows (4 independent FMA chains) ----
    {
        const int c = tid & 255;
        const int kq = tid >> 8;                  // 0..3
        const int k0 = kq * 38;
        const int k1 = (kq == 3) ? 150 : (k0 + 38);
        float a0 = 0.0f, a1 = 0.0f, a2 = 0.0f, a3 = 0.0f;
        for (int k = k0; k < k1; ++k) {
            const float w = W1[k * 256 + c];      // coalesced, one read per (k,c) per block
            a0 = fmaf(s[0][k], w, a0);
            a1 = fmaf(s[1][k], w, a1);
            a2 = fmaf(s[2][k], w, a2);
            a3 = fmaf(s[3][k], w, a3);
        }
        part1[kq][0][c] = a0;
        part1[kq][1][c] = a1;
        part1[kq][2][c] = a2;
        part1[kq][3][c] = a3;
    }
    __syncthreads();
    // combine layer-1 partials: 1024 threads = 4 rows x 256 cols
    {
        const int c = tid & 255;
        const int r = tid >> 8;
        float acc = b1[c] + ((part1[0][r][c] + part1[1][r][c]) + (part1[2][r][c] + part1[3][r][c]));
        h[r][c] = fmaxf(acc, 0.0f);
    }
    __syncthreads();

    // ---- phase 3: layer 2, k-split 4 ways x 128 cols; 4-row weight reuse ----
    if (tid < 512) {
        const int c = tid & 127;
        const int kq = tid >> 7;                  // 0..3
        const int kb = kq * 64;
        float a0 = 0.0f, a1 = 0.0f, a2 = 0.0f, a3 = 0.0f;
#pragma unroll 4
        for (int k = 0; k < 64; ++k) {
            const float w = W2[(kb + k) * 128 + c];
            a0 = fmaf(h[0][kb + k], w, a0);
            a1 = fmaf(h[1][kb + k], w, a1);
            a2 = fmaf(h[2][kb + k], w, a2);
            a3 = fmaf(h[3][kb + k], w, a3);
        }
        part2[kq][0][c] = a0;
        part2[kq][1][c] = a1;
        part2[kq][2][c] = a2;
        part2[kq][3][c] = a3;
    }
    __syncthreads();
    if (tid < 512) {
        const int c = tid & 127;
        const int r = tid >> 7;                   // 0..3
        out[(size_t)(r0 + r) * 128 + c] =
            b2[c] + ((part2[0][r][c] + part2[1][r][c]) + (part2[2][r][c] + part2[3][r][c]));
    }
}

extern "C" void kernel_launch(void* const* d_in, const int* in_sizes, int n_in,
                              void* d_out, int out_size, void* d_ws, size_t ws_size,
                              hipStream_t stream) {
    const int*   tok = (const int*)d_in[0];
    const float* W1  = (const float*)d_in[1];
    const float* b1  = (const float*)d_in[2];
    const float* W2  = (const float*)d_in[3];
    const float* b2  = (const float*)d_in[4];
    float* out = (float*)d_out;

    fused_kernel<<<256, 1024, 0, stream>>>(tok, W1, b1, W2, b2, out);
}